// Round 18
// baseline (144.504 us; speedup 1.0000x reference)
//
#include <hip/hip_runtime.h>

// TurboQuantKVCache -- Round 18: FLOAT32 output encoding (the actual fix).
// R16/R17 proved: harness upcasts bf16 inputs to f32 (rotation_T and
// boundaries both arrive as f32). R17 proved the kernel runs and bit-matches
// my host mirror -- so the lone mismatch was the OUTPUT encoding. d_out is
// float32[34,078,720] (136 MB): packed uint8 values stored as floats
// 0.0..255.0, norms as f32. Seventeen rounds of u16-bf16 writes into an f32
// buffer produced the immovable absmax=255 signature.
// Changes: all outputs f32 (float4 packed stores), f32 tail zeroing, f32
// rotation/boundaries reads (bf16-exact values), numpy-pairwise norm
// (8 strided accumulators, numpy's n<=128 unrolled path), single
// capture-safe launch on `stream`, no host APIs.
// Chain: f32->bf16 RNE snap; norm = np-pairwise f32 sum of squares, sqrt,
// bf16; (norm+eps) bf16; bf16 divide; GEMM = ascending-k single-acc fmaf
// (OpenBLAS sgemm order) on f32-upcast bf16; snap bf16; strict-< f32
// bucketize; (even<<4)|odd byte as f32.

__device__ __forceinline__ unsigned short tq_f2bf(float f) {
  unsigned int u = __float_as_uint(f);
  u += 0x7FFFu + ((u >> 16) & 1u);   // round-to-nearest-even
  return (unsigned short)(u >> 16);
}
__device__ __forceinline__ float tq_bf2f(unsigned short h) {
  return __uint_as_float(((unsigned int)h) << 16);
}

__global__ void TurboQuantKVCache_85942295593389_kernel(
    const float* kval, const float* vval,
    const int* ipos, const float* rotT,
    const float* bnd, float* out)
{
  __shared__ unsigned short Rb[128 * 128];   // 32 KB bf16 rotation, [k][c]
  __shared__ unsigned short xs[16][132];     // bf16 rows, stride 132
  __shared__ float nplus[16];

  const int tid = threadIdx.x;
  const int bid = blockIdx.x;

  const size_t PK = 16777216u;   // k_packed f32 elems (16*16384*64)
  const size_t NK = 262144u;     // k_norms f32 elems (16*16384)

  // ---- tail zeroing (f32): rows 4096..16383 of all four outputs ----
  {
    const uint4 z4 = make_uint4(0u, 0u, 0u, 0u);
    const size_t gtid = (size_t)bid * 256u + (size_t)tid;
    const size_t gstr = (size_t)8192u * 256u;
    // packed tails: 2 tensors x 16 heads x 196608 uint4 (12288 rows x 64 f32)
    for (size_t z = gtid; z < (size_t)6291456; z += gstr) {
      const unsigned t = (unsigned)(z / 196608u);
      const unsigned rem = (unsigned)(z % 196608u);
      uint4* base = (uint4*)(out + ((t >> 4) ? (PK + NK) : (size_t)0) +
                             (size_t)(t & 15) * 1048576u + 262144u);
      base[rem] = z4;
    }
    // norm tails: 2 tensors x 16 heads x 3072 uint4 (12288 f32)
    for (size_t z = gtid; z < (size_t)98304; z += gstr) {
      const unsigned t = (unsigned)(z / 3072u);
      const unsigned rem = (unsigned)(z % 3072u);
      uint4* base = (uint4*)(out + ((t >> 4) ? (2 * PK + NK) : PK) +
                             (size_t)(t & 15) * 16384u + 4096u);
      base[rem] = z4;
    }
  }

  // ---- boundaries: f32, bf16-exact values ----
  float bv[15];
#pragma unroll
  for (int q = 0; q < 15; ++q) bv[q] = bnd[q];

  // ---- compute: 16 rows/block; blocks 0..4095 -> k, 4096..8191 -> v ----
  const int kv = bid >> 12;
  const int rb = (bid & 4095) * 16;
  const float* src = kv ? vval : kval;
  float* pk = out + (kv ? (PK + NK) : (size_t)0);
  float* pn = out + (kv ? (2 * PK + NK) : PK);

  // stage rotation f32 -> bf16 LDS (values bf16-exact; truncation == RNE)
  for (int i = tid; i < 16384; i += 256)
    Rb[i] = (unsigned short)(__float_as_uint(rotT[i]) >> 16);

  // load 16 rows, snap to bf16; thread: row tid>>4, cols (tid&15)*8..+7
  {
    const int r = tid >> 4;
    const int k0 = (tid & 15) << 3;
    const float4* sp = (const float4*)(src + (size_t)(rb + r) * 128 + k0);
    float4 v0 = sp[0];
    float4 v1 = sp[1];
    xs[r][k0 + 0] = tq_f2bf(v0.x);
    xs[r][k0 + 1] = tq_f2bf(v0.y);
    xs[r][k0 + 2] = tq_f2bf(v0.z);
    xs[r][k0 + 3] = tq_f2bf(v0.w);
    xs[r][k0 + 4] = tq_f2bf(v1.x);
    xs[r][k0 + 5] = tq_f2bf(v1.y);
    xs[r][k0 + 6] = tq_f2bf(v1.z);
    xs[r][k0 + 7] = tq_f2bf(v1.w);
  }
  __syncthreads();

  // per-row norm: numpy pairwise (n=128 unrolled path, 8 accumulators)
  if (tid < 16) {
    const int r = tid;
    float r8[8];
#pragma unroll
    for (int j = 0; j < 8; ++j) {
      const float v = tq_bf2f(xs[r][j]);
      r8[j] = __fmul_rn(v, v);
    }
    for (int i = 8; i < 128; i += 8) {
#pragma unroll
      for (int j = 0; j < 8; ++j) {
        const float v = tq_bf2f(xs[r][i + j]);
        r8[j] = __fadd_rn(r8[j], __fmul_rn(v, v));
      }
    }
    const float ss = __fadd_rn(
        __fadd_rn(__fadd_rn(r8[0], r8[1]), __fadd_rn(r8[2], r8[3])),
        __fadd_rn(__fadd_rn(r8[4], r8[5]), __fadd_rn(r8[6], r8[7])));
    const float nrm = __fsqrt_rn(ss);
    const unsigned short nb = tq_f2bf(nrm);
    nplus[r] = tq_bf2f(tq_f2bf(__fadd_rn(tq_bf2f(nb), tq_bf2f(tq_f2bf(1e-10f)))));
    const int rg = rb + r;
    const int h = rg >> 12, t = rg & 4095;
    pn[(size_t)h * 16384 + ipos[t]] = tq_bf2f(nb);   // f32 of bf16 norm
  }
  __syncthreads();

  // normalize in place (bf16 divide: f32 div of bf16 operands, RNE -> bf16)
  for (int i = tid; i < 16 * 128; i += 256) {
    const int r = i >> 7, k = i & 127;
    xs[r][k] = tq_f2bf(__fdiv_rn(tq_bf2f(xs[r][k]), nplus[r]));
  }
  __syncthreads();

  // GEMM: thread -> row tid>>4, 8 cols at c0=(tid&15)*8
  // ascending-k single-accumulator fmaf chain (BLAS sgemm order)
  const int r = tid >> 4;
  const int c0 = (tid & 15) << 3;
  float acc[8];
#pragma unroll
  for (int j = 0; j < 8; ++j) acc[j] = 0.f;
  for (int k = 0; k < 128; ++k) {
    const uint4 bw = *(const uint4*)&Rb[k * 128 + c0];
    const float a = tq_bf2f(xs[r][k]);
    acc[0] = fmaf(a, tq_bf2f((unsigned short)(bw.x & 0xFFFFu)), acc[0]);
    acc[1] = fmaf(a, tq_bf2f((unsigned short)(bw.x >> 16)), acc[1]);
    acc[2] = fmaf(a, tq_bf2f((unsigned short)(bw.y & 0xFFFFu)), acc[2]);
    acc[3] = fmaf(a, tq_bf2f((unsigned short)(bw.y >> 16)), acc[3]);
    acc[4] = fmaf(a, tq_bf2f((unsigned short)(bw.z & 0xFFFFu)), acc[4]);
    acc[5] = fmaf(a, tq_bf2f((unsigned short)(bw.z >> 16)), acc[5]);
    acc[6] = fmaf(a, tq_bf2f((unsigned short)(bw.w & 0xFFFFu)), acc[6]);
    acc[7] = fmaf(a, tq_bf2f((unsigned short)(bw.w >> 16)), acc[7]);
  }

  // bucketize (strict <, f32 on bf16-snapped values) + pack + f32 scatter
  int idx[8];
#pragma unroll
  for (int j = 0; j < 8; ++j) {
    const float v = tq_bf2f(tq_f2bf(acc[j]));
    int c = 0;
#pragma unroll
    for (int q = 0; q < 15; ++q) c += (bv[q] < v) ? 1 : 0;
    idx[j] = c;
  }
  const int rg = rb + r;
  const int h = rg >> 12, t = rg & 4095;
  float* dst = pk + ((size_t)h * 16384 + ipos[t]) * 64 + (c0 >> 1);
  float4 wv;
  wv.x = (float)((idx[0] << 4) | idx[1]);
  wv.y = (float)((idx[2] << 4) | idx[3]);
  wv.z = (float)((idx[4] << 4) | idx[5]);
  wv.w = (float)((idx[6] << 4) | idx[7]);
  *(float4*)dst = wv;
}

extern "C" void kernel_launch(void* const* d_in, const int* in_sizes, int n_in,
                              void* d_out, int out_size, void* d_ws, size_t ws_size,
                              hipStream_t stream) {
  const int*   ipos = (const int*)d_in[0];
  const float* kval = (const float*)d_in[1];
  const float* vval = (const float*)d_in[2];
  const float* rotT = (const float*)d_in[3];   // bf16 upcast to f32 by harness
  const float* bnd  = (const float*)d_in[4];   // bf16 upcast to f32 by harness
  float* out = (float*)d_out;

  TurboQuantKVCache_85942295593389_kernel<<<dim3(8192), dim3(256), 0, stream>>>(
      kval, vval, ipos, rotT, bnd, out);
}

// Round 19
// 102.932 us; speedup vs baseline: 1.4039x; 1.4039x over previous
//
#include <hip/hip_runtime.h>

// TurboQuantKVCache -- Round 19: VALU-overhead reduction (bit-exact remap).
// R18 passed (absmax 0.0) at 168us rocprof: VALUBusy 86%, HBM 12.6% -> VALU-
// bound. Floors: FMA 27us, memory 32us. MFMA rejected: reordered accumulation
// flips ~20 buckets, high-nibble flip = err 16 > 5.1 threshold. All per-output
// sequential chains (np-pairwise norm, ascending-k fmaf GEMM) are preserved
// exactly; only the thread->work mapping changes:
//  - 4 rows x 8 cols per thread: 32 FMA per (8 b-unpack + 4 a-extract)
//  - a-operand loaded as b128 chunks (1 LDS read / row / 8k, was scalar/k)
//  - 64 rows/block (2048 blocks): 4x less rotation staging, float4-staged
//  - xs stride 136 u16: 4-address b128 reads land on disjoint banks
// Predicted: dur 168 -> ~90us, absmax stays 0.0, WRITE 133120KB unchanged.

#define TQ_ROWS 64
#define TQ_XPAD 136

__device__ __forceinline__ unsigned short tq_f2bf(float f) {
  unsigned int u = __float_as_uint(f);
  u += 0x7FFFu + ((u >> 16) & 1u);   // round-to-nearest-even
  return (unsigned short)(u >> 16);
}
__device__ __forceinline__ float tq_bf2f(unsigned short h) {
  return __uint_as_float(((unsigned int)h) << 16);
}
__device__ __forceinline__ float tq_lo2f(unsigned int w) {
  return __uint_as_float(w << 16);
}
__device__ __forceinline__ float tq_hi2f(unsigned int w) {
  return __uint_as_float(w & 0xFFFF0000u);
}

__global__ void TurboQuantKVCache_85942295593389_kernel(
    const float* kval, const float* vval,
    const int* ipos, const float* rotT,
    const float* bnd, float* out)
{
  __shared__ unsigned short Rb[128 * 128];        // 32 KB bf16 rotation [k][c]
  __shared__ unsigned short xs[TQ_ROWS][TQ_XPAD]; // 17.4 KB bf16 rows
  __shared__ float nplus[TQ_ROWS];

  const int tid = threadIdx.x;
  const int bid = blockIdx.x;

  const size_t PK = 16777216u;   // k_packed f32 elems
  const size_t NK = 262144u;     // k_norms  f32 elems

  // ---- tail zeroing (f32 rows 4096..16383 of all four outputs) ----
  {
    const uint4 z4 = make_uint4(0u, 0u, 0u, 0u);
    const size_t gtid = (size_t)bid * 256u + (size_t)tid;
    const size_t gstr = (size_t)2048u * 256u;
    for (size_t z = gtid; z < (size_t)6291456; z += gstr) {   // 12 iters
      const unsigned t = (unsigned)(z / 196608u);
      const unsigned rem = (unsigned)(z % 196608u);
      uint4* base = (uint4*)(out + ((t >> 4) ? (PK + NK) : (size_t)0) +
                             (size_t)(t & 15) * 1048576u + 262144u);
      base[rem] = z4;
    }
    for (size_t z = gtid; z < (size_t)98304; z += gstr) {
      const unsigned t = (unsigned)(z / 3072u);
      const unsigned rem = (unsigned)(z % 3072u);
      uint4* base = (uint4*)(out + ((t >> 4) ? (2 * PK + NK) : PK) +
                             (size_t)(t & 15) * 16384u + 4096u);
      base[rem] = z4;
    }
  }

  // ---- boundaries (f32, bf16-exact) ----
  float bv[15];
#pragma unroll
  for (int q = 0; q < 15; ++q) bv[q] = bnd[q];

  // ---- block -> 64 rows of k or v ----
  const int kv = bid >> 10;                  // 1024 blocks per source
  const int rb = (bid & 1023) * TQ_ROWS;
  const float* src = kv ? vval : kval;
  float* pk = out + (kv ? (PK + NK) : (size_t)0);
  float* pn = out + (kv ? (2 * PK + NK) : PK);

  // stage rotation f32 -> bf16 LDS (float4 loads; truncation == RNE here)
  {
    const float4* r4 = (const float4*)rotT;
    for (int i = tid; i < 4096; i += 256) {
      const float4 v = r4[i];
      ushort4 w;
      w.x = (unsigned short)(__float_as_uint(v.x) >> 16);
      w.y = (unsigned short)(__float_as_uint(v.y) >> 16);
      w.z = (unsigned short)(__float_as_uint(v.z) >> 16);
      w.w = (unsigned short)(__float_as_uint(v.w) >> 16);
      *(ushort4*)&Rb[i * 4] = w;
    }
  }
  // stage 64 rows, snap to bf16: 2048 float4, 8 per thread
  {
#pragma unroll
    for (int j = 0; j < 8; ++j) {
      const int idx = tid + j * 256;
      const int r = idx >> 5;              // 32 float4 per row
      const int k0 = (idx & 31) << 2;
      const float4 v = *(const float4*)(src + (size_t)(rb + r) * 128 + k0);
      ushort4 w;
      w.x = tq_f2bf(v.x);
      w.y = tq_f2bf(v.y);
      w.z = tq_f2bf(v.z);
      w.w = tq_f2bf(v.w);
      *(ushort4*)&xs[r][k0] = w;
    }
  }
  __syncthreads();

  // ---- per-row norm: numpy pairwise (8 strided accumulators) ----
  if (tid < TQ_ROWS) {
    const int r = tid;
    float r8[8];
#pragma unroll
    for (int j = 0; j < 8; ++j) {
      const float v = tq_bf2f(xs[r][j]);
      r8[j] = __fmul_rn(v, v);
    }
    for (int i = 8; i < 128; i += 8) {
#pragma unroll
      for (int j = 0; j < 8; ++j) {
        const float v = tq_bf2f(xs[r][i + j]);
        r8[j] = __fadd_rn(r8[j], __fmul_rn(v, v));
      }
    }
    const float ss = __fadd_rn(
        __fadd_rn(__fadd_rn(r8[0], r8[1]), __fadd_rn(r8[2], r8[3])),
        __fadd_rn(__fadd_rn(r8[4], r8[5]), __fadd_rn(r8[6], r8[7])));
    const float nrm = __fsqrt_rn(ss);
    const unsigned short nb = tq_f2bf(nrm);
    nplus[r] = tq_bf2f(tq_f2bf(__fadd_rn(tq_bf2f(nb), tq_bf2f(tq_f2bf(1e-10f)))));
    const int rg = rb + r;
    const int h = rg >> 12, t = rg & 4095;
    pn[(size_t)h * 16384 + ipos[t]] = tq_bf2f(nb);
  }
  __syncthreads();

  // ---- normalize in place ----
  for (int i = tid; i < TQ_ROWS * 128; i += 256) {
    const int r = i >> 7, k = i & 127;
    xs[r][k] = tq_f2bf(__fdiv_rn(tq_bf2f(xs[r][k]), nplus[r]));
  }
  __syncthreads();

  // ---- GEMM: thread -> 4 rows x 8 cols; ascending-k single-acc fmaf ----
  const int c0 = (tid & 15) << 3;
  const int r0 = (tid >> 4) << 2;
  float acc[4][8];
#pragma unroll
  for (int rr = 0; rr < 4; ++rr)
#pragma unroll
    for (int j = 0; j < 8; ++j) acc[rr][j] = 0.f;

  for (int kb = 0; kb < 128; kb += 8) {
    uint4 aw[4];
#pragma unroll
    for (int rr = 0; rr < 4; ++rr)
      aw[rr] = *(const uint4*)&xs[r0 + rr][kb];
#pragma unroll
    for (int kk = 0; kk < 8; ++kk) {
      const uint4 bw = *(const uint4*)&Rb[(kb + kk) * 128 + c0];
      float b[8];
      b[0] = tq_lo2f(bw.x); b[1] = tq_hi2f(bw.x);
      b[2] = tq_lo2f(bw.y); b[3] = tq_hi2f(bw.y);
      b[4] = tq_lo2f(bw.z); b[5] = tq_hi2f(bw.z);
      b[6] = tq_lo2f(bw.w); b[7] = tq_hi2f(bw.w);
#pragma unroll
      for (int rr = 0; rr < 4; ++rr) {
        const unsigned int word = ((const unsigned int*)&aw[rr])[kk >> 1];
        const float a = (kk & 1) ? tq_hi2f(word) : tq_lo2f(word);
        acc[rr][0] = fmaf(a, b[0], acc[rr][0]);
        acc[rr][1] = fmaf(a, b[1], acc[rr][1]);
        acc[rr][2] = fmaf(a, b[2], acc[rr][2]);
        acc[rr][3] = fmaf(a, b[3], acc[rr][3]);
        acc[rr][4] = fmaf(a, b[4], acc[rr][4]);
        acc[rr][5] = fmaf(a, b[5], acc[rr][5]);
        acc[rr][6] = fmaf(a, b[6], acc[rr][6]);
        acc[rr][7] = fmaf(a, b[7], acc[rr][7]);
      }
    }
  }

  // ---- bucketize (strict <, f32 on bf16-snapped) + pack + f32 store ----
#pragma unroll
  for (int rr = 0; rr < 4; ++rr) {
    int idx[8];
#pragma unroll
    for (int j = 0; j < 8; ++j) {
      const float v = tq_bf2f(tq_f2bf(acc[rr][j]));
      int c = 0;
#pragma unroll
      for (int q = 0; q < 15; ++q) c += (bv[q] < v) ? 1 : 0;
      idx[j] = c;
    }
    const int rg = rb + r0 + rr;
    const int h = rg >> 12, t = rg & 4095;
    float* dst = pk + ((size_t)h * 16384 + ipos[t]) * 64 + (c0 >> 1);
    float4 wv;
    wv.x = (float)((idx[0] << 4) | idx[1]);
    wv.y = (float)((idx[2] << 4) | idx[3]);
    wv.z = (float)((idx[4] << 4) | idx[5]);
    wv.w = (float)((idx[6] << 4) | idx[7]);
    *(float4*)dst = wv;
  }
}

extern "C" void kernel_launch(void* const* d_in, const int* in_sizes, int n_in,
                              void* d_out, int out_size, void* d_ws, size_t ws_size,
                              hipStream_t stream) {
  const int*   ipos = (const int*)d_in[0];
  const float* kval = (const float*)d_in[1];
  const float* vval = (const float*)d_in[2];
  const float* rotT = (const float*)d_in[3];   // bf16 values upcast to f32
  const float* bnd  = (const float*)d_in[4];   // bf16 values upcast to f32
  float* out = (float*)d_out;

  TurboQuantKVCache_85942295593389_kernel<<<dim3(2048), dim3(256), 0, stream>>>(
      kval, vval, ipos, rotT, bnd, out);
}